// Round 7
// baseline (5212.754 us; speedup 1.0000x reference)
//
#include <hip/hip_runtime.h>
#include <hip/hip_bf16.h>
#include <math.h>

#define DIM 64
#define NK_MAX 6656      // max bucket*tile keys supported (N<=106k)
#define PCHUNK 16384
typedef _Float16 f16;
typedef unsigned int uint32;

// ---------------- histogram over (bucket,srctile) keys, LDS-staged ----------------
__global__ __launch_bounds__(256) void k_hist(const int* __restrict__ row, const int* __restrict__ col,
                                              int* __restrict__ bkcnt, int E, int nk) {
  __shared__ int lc[NK_MAX];
  int tid = threadIdx.x;
  for (int i = tid; i < nk; i += 256) lc[i] = 0;
  __syncthreads();
  int b0 = blockIdx.x * PCHUNK;
  int b1 = min(E, b0 + PCHUNK);
  for (int e = b0 + tid; e < b1; e += 256) {
    int k = ((col[e] >> 6) << 2) | (row[e] >> 15);
    atomicAdd(&lc[k], 1);
  }
  __syncthreads();
  for (int i = tid; i < nk; i += 256) { int c = lc[i]; if (c) atomicAdd(&bkcnt[i], c); }
}

// ---------------- exclusive scan over nk keys (single block) ----------------
__global__ __launch_bounds__(256) void k_scank(const int* __restrict__ cnt, int* __restrict__ offs,
                                               int* __restrict__ cur, int nk) {
  __shared__ int ps[256];
  int t = threadIdx.x;
  int per = (nk + 255) >> 8;
  int b0 = t * per;
  int s = 0;
  for (int i = 0; i < per; ++i) { int idx = b0 + i; if (idx < nk) s += cnt[idx]; }
  ps[t] = s;
  __syncthreads();
  for (int d = 1; d < 256; d <<= 1) {
    int v = (t >= d) ? ps[t - d] : 0;
    __syncthreads();
    if (t >= d) ps[t] += v;
    __syncthreads();
  }
  int run = ps[t] - s;
  for (int i = 0; i < per; ++i) {
    int idx = b0 + i;
    if (idx < nk) { offs[idx] = run; cur[idx] = run; run += cnt[idx]; }
  }
  if (t == 255) offs[nk] = run;   // == E
}

// ---------------- partition edges into (bucket,srctile) segments ----------------
__global__ __launch_bounds__(256) void k_part(const int* __restrict__ row, const int* __restrict__ col,
                                              int* __restrict__ bcur, uint32* __restrict__ recs,
                                              int E, int nk) {
  __shared__ int lc[NK_MAX];
  __shared__ int gb[NK_MAX];
  int tid = threadIdx.x;
  for (int i = tid; i < nk; i += 256) lc[i] = 0;
  __syncthreads();
  int b0 = blockIdx.x * PCHUNK;
  int b1 = min(E, b0 + PCHUNK);
  for (int e = b0 + tid; e < b1; e += 256) {
    int k = ((col[e] >> 6) << 2) | (row[e] >> 15);
    atomicAdd(&lc[k], 1);
  }
  __syncthreads();
  for (int i = tid; i < nk; i += 256) {
    int c = lc[i];
    if (c) { gb[i] = atomicAdd(&bcur[i], c); lc[i] = 0; }
  }
  __syncthreads();
  for (int e = b0 + tid; e < b1; e += 256) {
    int r = row[e], c = col[e];
    int k = ((c >> 6) << 2) | (r >> 15);
    int pos = gb[k] + atomicAdd(&lc[k], 1);
    recs[pos] = ((uint32)r << 6) | (uint32)(c & 63);
  }
}

// ---------------- per-node degree (from records) -> dis = rsqrt(deg+1) ----------------
__global__ __launch_bounds__(256) void k_dis2(const uint32* __restrict__ recs, const int* __restrict__ keyoffs,
                                              float* __restrict__ dis, int N) {
  __shared__ int lc[64];
  int b = blockIdx.x, tid = threadIdx.x;
  if (tid < 64) lc[tid] = 0;
  __syncthreads();
  int beg = keyoffs[b << 2], end = keyoffs[(b << 2) + 4];
  for (int p = beg + tid; p < end; p += 256) atomicAdd(&lc[recs[p] & 63], 1);
  __syncthreads();
  int base = b << 6;
  if (tid < 64 && base + tid < N) dis[base + tid] = rsqrtf((float)(lc[tid] + 1));
}

// ---------------- GEMM layer 1: xl = dis * (x @ W1), fp16 out ----------------
__global__ __launch_bounds__(256) void k_gemm_in(const float* __restrict__ x, const float* __restrict__ W,
                                                 const float* __restrict__ dis, f16* __restrict__ xl,
                                                 int N, int FIN) {
  __shared__ float Ws[128 * DIM];
  __shared__ float vbuf[4][128];
  int tid = threadIdx.x;
  for (int i = tid; i < FIN * DIM; i += 256) Ws[i] = W[i];
  __syncthreads();
  int wave = tid >> 6, lane = tid & 63;
  int stride = gridDim.x * 4;
  for (int n = blockIdx.x * 4 + wave; n < N; n += stride) {
    const float* xr = x + (size_t)n * FIN;
    for (int k = lane; k < FIN; k += 64) vbuf[wave][k] = xr[k];
    float acc = 0.f;
#pragma unroll 16
    for (int k = 0; k < FIN; ++k) acc = fmaf(vbuf[wave][k], Ws[k * DIM + lane], acc);
    xl[(size_t)n * DIM + lane] = (f16)(acc * dis[n]);
  }
}

// ---------------- GEMM layers 2-4: xl = dis * (bn(y) @ W), fp16 out ----------------
__global__ __launch_bounds__(256) void k_gemm_bn(const float* __restrict__ y, const float* __restrict__ W,
                                                 const float* __restrict__ gam, const float* __restrict__ bet,
                                                 const float* __restrict__ s1, const float* __restrict__ s2,
                                                 const float* __restrict__ dis, f16* __restrict__ xl, int N) {
  __shared__ float Ws[DIM * DIM];
  __shared__ float aL[DIM], cL[DIM];
  __shared__ float vbuf[4][DIM];
  int tid = threadIdx.x;
  for (int i = tid; i < DIM * DIM; i += 256) Ws[i] = W[i];
  if (tid < DIM) {
    float invN = 1.0f / (float)N;
    float m = s1[tid] * invN;
    float var = s2[tid] * invN - m * m;
    float inv = rsqrtf(var + 1e-5f);
    float a = gam[tid] * inv;
    aL[tid] = a;
    cL[tid] = fmaf(-m, a, bet[tid]);
  }
  __syncthreads();
  int wave = tid >> 6, lane = tid & 63;
  int stride = gridDim.x * 4;
  for (int n = blockIdx.x * 4 + wave; n < N; n += stride) {
    vbuf[wave][lane] = fmaf(aL[lane], y[(size_t)n * DIM + lane], cL[lane]);
    float acc = 0.f;
#pragma unroll
    for (int k = 0; k < DIM; ++k) acc = fmaf(vbuf[wave][k], Ws[k * DIM + lane], acc);
    xl[(size_t)n * DIM + lane] = (f16)(acc * dis[n]);
  }
}

// ---------------- aggregation: block-per-bucket, LDS accumulator ----------------
__global__ __launch_bounds__(256) void k_agg(const f16* __restrict__ xl, const uint32* __restrict__ recs,
                                             const int* __restrict__ keyoffs, const float* __restrict__ dis,
                                             const float* __restrict__ bias, float* __restrict__ y,
                                             float* __restrict__ s1, float* __restrict__ s2, int N) {
  __shared__ float acc[64 * DIM];   // 16 KB
  __shared__ float rbuf[256];
  int b = blockIdx.x;
  int tid = threadIdx.x;
  int base = b << 6;
  int nn = min(64, N - base);
  int lim = nn << 6;
  const f16* xb = xl + ((size_t)base << 6);
  for (int i = tid; i < 64 * DIM; i += 256) acc[i] = (i < lim) ? (float)xb[i] : 0.f;   // self-loop
  __syncthreads();
  int lane = tid & 63, wave = tid >> 6;
  int beg = keyoffs[b << 2], end = keyoffs[(b << 2) + 4];
  int p = beg + wave;
  for (; p + 12 < end; p += 16) {
    uint32 r0 = recs[p], r1 = recs[p + 4], r2 = recs[p + 8], r3 = recs[p + 12];
    float v0 = (float)xl[((size_t)(r0 >> 6) << 6) + lane];
    float v1 = (float)xl[((size_t)(r1 >> 6) << 6) + lane];
    float v2 = (float)xl[((size_t)(r2 >> 6) << 6) + lane];
    float v3 = (float)xl[((size_t)(r3 >> 6) << 6) + lane];
    atomicAdd(&acc[((r0 & 63) << 6) + lane], v0);
    atomicAdd(&acc[((r1 & 63) << 6) + lane], v1);
    atomicAdd(&acc[((r2 & 63) << 6) + lane], v2);
    atomicAdd(&acc[((r3 & 63) << 6) + lane], v3);
  }
  for (; p < end; p += 4) {
    uint32 r = recs[p];
    float v = (float)xl[((size_t)(r >> 6) << 6) + lane];
    atomicAdd(&acc[((r & 63) << 6) + lane], v);
  }
  __syncthreads();
  float ls = 0.f, lq = 0.f;
  float bb = bias[lane];
  for (int j = wave; j < nn; j += 4) {
    int n = base + j;
    float yv = fmaxf(fmaf(dis[n], acc[(j << 6) + lane], bb), 0.f);
    y[((size_t)n << 6) + lane] = yv;
    ls += yv;
    lq = fmaf(yv, yv, lq);
  }
  rbuf[tid] = ls;
  __syncthreads();
  if (tid < 64) atomicAdd(&s1[tid], rbuf[tid] + rbuf[tid + 64] + rbuf[tid + 128] + rbuf[tid + 192]);
  __syncthreads();
  rbuf[tid] = lq;
  __syncthreads();
  if (tid < 64) atomicAdd(&s2[tid], rbuf[tid] + rbuf[tid + 64] + rbuf[tid + 128] + rbuf[tid + 192]);
}

// ---------------- global mean pool: segmented (batch sorted), BN4 fused ----------------
__global__ __launch_bounds__(256) void k_pool(const float* __restrict__ y, const float* __restrict__ gam,
                                              const float* __restrict__ bet, const float* __restrict__ s1,
                                              const float* __restrict__ s2, const int* __restrict__ batch,
                                              float* __restrict__ pooled, float* __restrict__ gcnt,
                                              int N, int chunk) {
  __shared__ float aL[DIM], cL[DIM];
  int tid = threadIdx.x;
  if (tid < DIM) {
    float invN = 1.0f / (float)N;
    float m = s1[tid] * invN;
    float var = s2[tid] * invN - m * m;
    float inv = rsqrtf(var + 1e-5f);
    float a = gam[tid] * inv;
    aL[tid] = a;
    cL[tid] = fmaf(-m, a, bet[tid]);
  }
  __syncthreads();
  int wave = tid >> 6, lane = tid & 63;
  int wid = blockIdx.x * 4 + wave;
  int n0 = wid * chunk;
  int n1 = min(N, n0 + chunk);
  if (n0 >= N) return;
  int cur_g = batch[n0];
  float acc = 0.f;
  int cntn = 0;
  for (int n = n0; n < n1; ++n) {
    int gi = batch[n];
    if (gi != cur_g) {
      atomicAdd(&pooled[(size_t)cur_g * DIM + lane], acc);
      if (lane == 0) atomicAdd(&gcnt[cur_g], (float)cntn);
      cur_g = gi; acc = 0.f; cntn = 0;
    }
    acc += fmaf(aL[lane], y[(size_t)n * DIM + lane], cL[lane]);
    ++cntn;
  }
  atomicAdd(&pooled[(size_t)cur_g * DIM + lane], acc);
  if (lane == 0) atomicAdd(&gcnt[cur_g], (float)cntn);
}

// ---------------- head: mean, fc, log_softmax ----------------
__global__ __launch_bounds__(256) void k_head(const float* __restrict__ pooled, const float* __restrict__ gcnt,
                                              const float* __restrict__ fcW, const float* __restrict__ fcb,
                                              float* __restrict__ out, int G, int C) {
  int g = blockIdx.x * 256 + threadIdx.x;
  if (g >= G) return;
  float z[16];
  for (int c = 0; c < C; ++c) z[c] = fcb[c];
  float inv = 1.f / fmaxf(gcnt[g], 1.f);
  for (int f = 0; f < DIM; ++f) {
    float p = pooled[(size_t)g * DIM + f] * inv;
    for (int c = 0; c < C; ++c) z[c] = fmaf(p, fcW[f * C + c], z[c]);
  }
  float m = -1e30f;
  for (int c = 0; c < C; ++c) m = fmaxf(m, z[c]);
  float s = 0.f;
  for (int c = 0; c < C; ++c) s += expf(z[c] - m);
  float ls = logf(s);
  for (int c = 0; c < C; ++c) out[(size_t)g * C + c] = z[c] - m - ls;
}

extern "C" void kernel_launch(void* const* d_in, const int* in_sizes, int n_in,
                              void* d_out, int out_size, void* d_ws, size_t ws_size,
                              hipStream_t stream) {
  const float* x    = (const float*)d_in[0];
  const int*   ei   = (const int*)d_in[1];
  const int*   batch= (const int*)d_in[2];
  const float* W1 = (const float*)d_in[4];
  const float* b1 = (const float*)d_in[5];
  const float* W2 = (const float*)d_in[6];
  const float* b2 = (const float*)d_in[7];
  const float* W3 = (const float*)d_in[8];
  const float* b3 = (const float*)d_in[9];
  const float* W4 = (const float*)d_in[10];
  const float* b4 = (const float*)d_in[11];
  const float* g1 = (const float*)d_in[12];
  const float* be1= (const float*)d_in[13];
  const float* g2 = (const float*)d_in[14];
  const float* be2= (const float*)d_in[15];
  const float* g3 = (const float*)d_in[16];
  const float* be3= (const float*)d_in[17];
  const float* g4 = (const float*)d_in[18];
  const float* be4= (const float*)d_in[19];
  const float* fcW= (const float*)d_in[20];
  const float* fcb= (const float*)d_in[21];
  float* out = (float*)d_out;

  int N   = in_sizes[2];
  int E   = in_sizes[1] / 2;
  int FIN = in_sizes[4] / DIM;
  int C   = in_sizes[21];
  int G   = out_size / C;

  int nb = (N + 63) >> 6;         // buckets of 64 target nodes
  int nk = nb << 2;               // x4 source tiles (src>>15)

  char* ws = (char*)d_ws;
  size_t off = 0;
  auto alloc = [&](size_t bytes) { size_t o = off; off = (off + bytes + 255) & ~(size_t)255; return o; };
  // zero-init group (must be first / contiguous)
  size_t o_bkc  = alloc((size_t)nk * 4);
  size_t o_bn   = alloc(4 * 2 * 64 * 4);
  size_t o_pool = alloc((size_t)G * DIM * 4);
  size_t o_gcnt = alloc((size_t)G * 4);
  size_t zero_bytes = off;
  // no-init group
  size_t o_ko   = alloc((size_t)(nk + 1) * 4);
  size_t o_cur  = alloc((size_t)nk * 4);
  size_t o_dis  = alloc((size_t)N * 4);
  size_t o_recs = alloc((size_t)E * 4);
  size_t o_xl   = alloc((size_t)N * DIM * 2);   // fp16
  size_t o_y    = alloc((size_t)N * DIM * 4);
  (void)ws_size;

  int*    bkcnt  = (int*)(ws + o_bkc);
  float*  bn     = (float*)(ws + o_bn);
  float*  pooled = (float*)(ws + o_pool);
  float*  gcnt   = (float*)(ws + o_gcnt);
  int*    keyoffs= (int*)(ws + o_ko);
  int*    bcur   = (int*)(ws + o_cur);
  float*  dis    = (float*)(ws + o_dis);
  uint32* recs   = (uint32*)(ws + o_recs);
  f16*    xl     = (f16*)(ws + o_xl);
  float*  y      = (float*)(ws + o_y);

  hipMemsetAsync(d_ws, 0, zero_bytes, stream);

  const int* row  = ei;
  const int* colp = ei + E;
  int pblk = (E + PCHUNK - 1) / PCHUNK;

  k_hist<<<pblk, 256, 0, stream>>>(row, colp, bkcnt, E, nk);
  k_scank<<<1, 256, 0, stream>>>(bkcnt, keyoffs, bcur, nk);
  k_part<<<pblk, 256, 0, stream>>>(row, colp, bcur, recs, E, nk);
  k_dis2<<<nb, 256, 0, stream>>>(recs, keyoffs, dis, N);

  // Layer 1
  k_gemm_in<<<1024, 256, 0, stream>>>(x, W1, dis, xl, N, FIN);
  k_agg<<<nb, 256, 0, stream>>>(xl, recs, keyoffs, dis, b1, y, bn + 0, bn + 64, N);
  // Layer 2 (applies BN1 on the fly)
  k_gemm_bn<<<2048, 256, 0, stream>>>(y, W2, g1, be1, bn + 0, bn + 64, dis, xl, N);
  k_agg<<<nb, 256, 0, stream>>>(xl, recs, keyoffs, dis, b2, y, bn + 128, bn + 192, N);
  // Layer 3
  k_gemm_bn<<<2048, 256, 0, stream>>>(y, W3, g2, be2, bn + 128, bn + 192, dis, xl, N);
  k_agg<<<nb, 256, 0, stream>>>(xl, recs, keyoffs, dis, b3, y, bn + 256, bn + 320, N);
  // Layer 4
  k_gemm_bn<<<2048, 256, 0, stream>>>(y, W4, g3, be3, bn + 256, bn + 320, dis, xl, N);
  k_agg<<<nb, 256, 0, stream>>>(xl, recs, keyoffs, dis, b4, y, bn + 384, bn + 448, N);
  // Pool (applies BN4) + head
  int nwaves = 2048;
  int chunk = (N + nwaves - 1) / nwaves;
  k_pool<<<nwaves / 4, 256, 0, stream>>>(y, g4, be4, bn + 384, bn + 448, batch, pooled, gcnt, N, chunk);
  k_head<<<(G + 255) / 256, 256, 0, stream>>>(pooled, gcnt, fcW, fcb, out, G, C);
}

// Round 8
// 998.378 us; speedup vs baseline: 5.2212x; 5.2212x over previous
//
#include <hip/hip_runtime.h>
#include <hip/hip_bf16.h>
#include <math.h>

#define DIM 64
#define NBK_MAX 512       // max 256-node buckets (N <= 131072)
#define PCHUNK 4096
typedef _Float16 f16;
typedef unsigned int uint32;

// ---------------- histogram over 256-node target buckets ----------------
__global__ __launch_bounds__(256) void k_hist(const int* __restrict__ col, int* __restrict__ bkcnt,
                                              int E, int nbk) {
  __shared__ int lc[NBK_MAX];
  int tid = threadIdx.x;
  for (int i = tid; i < nbk; i += 256) lc[i] = 0;
  __syncthreads();
  int b0 = blockIdx.x * PCHUNK;
  int b1 = min(E, b0 + PCHUNK);
  for (int e = b0 + tid; e < b1; e += 256) atomicAdd(&lc[col[e] >> 8], 1);
  __syncthreads();
  for (int i = tid; i < nbk; i += 256) { int c = lc[i]; if (c) atomicAdd(&bkcnt[i], c); }
}

// ---------------- exclusive scan over nbk bucket counts (single block) ----------------
__global__ __launch_bounds__(256) void k_scank(const int* __restrict__ cnt, int* __restrict__ offs,
                                               int* __restrict__ cur, int nbk) {
  __shared__ int ps[256];
  int t = threadIdx.x;
  int per = (nbk + 255) >> 8;
  int b0 = t * per;
  int s = 0;
  for (int i = 0; i < per; ++i) { int idx = b0 + i; if (idx < nbk) s += cnt[idx]; }
  ps[t] = s;
  __syncthreads();
  for (int d = 1; d < 256; d <<= 1) {
    int v = (t >= d) ? ps[t - d] : 0;
    __syncthreads();
    if (t >= d) ps[t] += v;
    __syncthreads();
  }
  int run = ps[t] - s;
  for (int i = 0; i < per; ++i) {
    int idx = b0 + i;
    if (idx < nbk) { offs[idx] = run; cur[idx] = run; run += cnt[idx]; }
  }
  if (t == 255) offs[nbk] = run;   // == E
}

// ---------------- partition edges into 256-node-bucket segments ----------------
// record = (src << 8) | (col & 255); src < 2^17, fits 25 bits
__global__ __launch_bounds__(256) void k_part(const int* __restrict__ row, const int* __restrict__ col,
                                              int* __restrict__ bcur, uint32* __restrict__ recs,
                                              int E, int nbk) {
  __shared__ int lc[NBK_MAX];
  __shared__ int gb[NBK_MAX];
  int tid = threadIdx.x;
  for (int i = tid; i < nbk; i += 256) lc[i] = 0;
  __syncthreads();
  int b0 = blockIdx.x * PCHUNK;
  int b1 = min(E, b0 + PCHUNK);
  for (int e = b0 + tid; e < b1; e += 256) atomicAdd(&lc[col[e] >> 8], 1);
  __syncthreads();
  for (int i = tid; i < nbk; i += 256) {
    int c = lc[i];
    if (c) { gb[i] = atomicAdd(&bcur[i], c); lc[i] = 0; }
  }
  __syncthreads();
  for (int e = b0 + tid; e < b1; e += 256) {
    int r = row[e], c = col[e];
    int k = c >> 8;
    int pos = gb[k] + atomicAdd(&lc[k], 1);
    recs[pos] = ((uint32)r << 8) | (uint32)(c & 255);
  }
}

// ---------------- per-bucket counting sort -> per-node CSR + deg + dis ----------------
// block b owns nodes [b*256, b*256+256); bucket segment is [keyoffs[b], keyoffs[b+1])
__global__ __launch_bounds__(256) void k_sort2(const uint32* __restrict__ recs, const int* __restrict__ keyoffs,
                                               int* __restrict__ csrs, int* __restrict__ offs,
                                               int* __restrict__ cnt, float* __restrict__ dis, int N) {
  __shared__ int lc[256];
  __shared__ int ps[256];
  __shared__ int pos[256];
  int b = blockIdx.x, tid = threadIdx.x;
  lc[tid] = 0;
  __syncthreads();
  int beg = keyoffs[b], end = keyoffs[b + 1];
  for (int p = beg + tid; p < end; p += 256) atomicAdd(&lc[recs[p] & 255], 1);
  __syncthreads();
  int my = lc[tid];
  ps[tid] = my;
  __syncthreads();
  for (int d = 1; d < 256; d <<= 1) {
    int v = (tid >= d) ? ps[tid - d] : 0;
    __syncthreads();
    if (tid >= d) ps[tid] += v;
    __syncthreads();
  }
  int epf = ps[tid] - my;           // exclusive prefix within bucket
  pos[tid] = beg + epf;
  int node = (b << 8) + tid;
  if (node < N) {
    offs[node] = beg + epf;
    cnt[node] = my;
    dis[node] = rsqrtf((float)(my + 1));
  }
  __syncthreads();
  for (int p = beg + tid; p < end; p += 256) {
    uint32 r = recs[p];
    int q = atomicAdd(&pos[r & 255], 1);
    csrs[q] = (int)(r >> 8);
  }
}

// ---------------- GEMM layer 1: xl = dis * (x @ W1), fp16 out ----------------
__global__ __launch_bounds__(256) void k_gemm_in(const float* __restrict__ x, const float* __restrict__ W,
                                                 const float* __restrict__ dis, f16* __restrict__ xl,
                                                 int N, int FIN) {
  __shared__ float Ws[128 * DIM];
  __shared__ float vbuf[4][128];
  int tid = threadIdx.x;
  for (int i = tid; i < FIN * DIM; i += 256) Ws[i] = W[i];
  __syncthreads();
  int wave = tid >> 6, lane = tid & 63;
  int stride = gridDim.x * 4;
  for (int n = blockIdx.x * 4 + wave; n < N; n += stride) {
    const float* xr = x + (size_t)n * FIN;
    for (int k = lane; k < FIN; k += 64) vbuf[wave][k] = xr[k];
    float acc = 0.f;
#pragma unroll 16
    for (int k = 0; k < FIN; ++k) acc = fmaf(vbuf[wave][k], Ws[k * DIM + lane], acc);
    xl[(size_t)n * DIM + lane] = (f16)(acc * dis[n]);
  }
}

// ---------------- GEMM layers 2-4: xl = dis * (bn(y) @ W), fp16 out ----------------
__global__ __launch_bounds__(256) void k_gemm_bn(const float* __restrict__ y, const float* __restrict__ W,
                                                 const float* __restrict__ gam, const float* __restrict__ bet,
                                                 const float* __restrict__ s1, const float* __restrict__ s2,
                                                 const float* __restrict__ dis, f16* __restrict__ xl, int N) {
  __shared__ float Ws[DIM * DIM];
  __shared__ float aL[DIM], cL[DIM];
  __shared__ float vbuf[4][DIM];
  int tid = threadIdx.x;
  for (int i = tid; i < DIM * DIM; i += 256) Ws[i] = W[i];
  if (tid < DIM) {
    float invN = 1.0f / (float)N;
    float m = s1[tid] * invN;
    float var = s2[tid] * invN - m * m;
    float inv = rsqrtf(var + 1e-5f);
    float a = gam[tid] * inv;
    aL[tid] = a;
    cL[tid] = fmaf(-m, a, bet[tid]);
  }
  __syncthreads();
  int wave = tid >> 6, lane = tid & 63;
  int stride = gridDim.x * 4;
  for (int n = blockIdx.x * 4 + wave; n < N; n += stride) {
    vbuf[wave][lane] = fmaf(aL[lane], y[(size_t)n * DIM + lane], cL[lane]);
    float acc = 0.f;
#pragma unroll
    for (int k = 0; k < DIM; ++k) acc = fmaf(vbuf[wave][k], Ws[k * DIM + lane], acc);
    xl[(size_t)n * DIM + lane] = (f16)(acc * dis[n]);
  }
}

// ---------------- aggregation: per-node register accumulate, unroll 8, BN sums fused ----------------
__global__ __launch_bounds__(256) void k_agg(const f16* __restrict__ xl, const int* __restrict__ offs,
                                             const int* __restrict__ cnt, const int* __restrict__ src,
                                             const float* __restrict__ dis, const float* __restrict__ bias,
                                             float* __restrict__ y, float* __restrict__ s1,
                                             float* __restrict__ s2, int N) {
  int tid = threadIdx.x;
  int wave = tid >> 6, lane = tid & 63;
  float ls = 0.f, lq = 0.f;
  float b = bias[lane];
  int stride = gridDim.x * 4;
  for (int n = blockIdx.x * 4 + wave; n < N; n += stride) {
    float di = dis[n];
    float acc = (float)xl[((size_t)n << 6) + lane];  // self-loop (pre-scaled)
    int p = offs[n];
    int end = p + cnt[n];
    for (; p + 7 < end; p += 8) {
      int a0 = src[p],     a1 = src[p + 1], a2 = src[p + 2], a3 = src[p + 3];
      int a4 = src[p + 4], a5 = src[p + 5], a6 = src[p + 6], a7 = src[p + 7];
      float v0 = (float)xl[((size_t)a0 << 6) + lane];
      float v1 = (float)xl[((size_t)a1 << 6) + lane];
      float v2 = (float)xl[((size_t)a2 << 6) + lane];
      float v3 = (float)xl[((size_t)a3 << 6) + lane];
      float v4 = (float)xl[((size_t)a4 << 6) + lane];
      float v5 = (float)xl[((size_t)a5 << 6) + lane];
      float v6 = (float)xl[((size_t)a6 << 6) + lane];
      float v7 = (float)xl[((size_t)a7 << 6) + lane];
      acc += ((v0 + v1) + (v2 + v3)) + ((v4 + v5) + (v6 + v7));
    }
    for (; p < end; ++p) acc += (float)xl[((size_t)src[p] << 6) + lane];
    float yv = fmaxf(fmaf(di, acc, b), 0.f);
    y[((size_t)n << 6) + lane] = yv;
    ls += yv;
    lq = fmaf(yv, yv, lq);
  }
  __shared__ float rbuf[256];
  rbuf[tid] = ls;
  __syncthreads();
  if (tid < 64) atomicAdd(&s1[tid], rbuf[tid] + rbuf[tid + 64] + rbuf[tid + 128] + rbuf[tid + 192]);
  __syncthreads();
  rbuf[tid] = lq;
  __syncthreads();
  if (tid < 64) atomicAdd(&s2[tid], rbuf[tid] + rbuf[tid + 64] + rbuf[tid + 128] + rbuf[tid + 192]);
}

// ---------------- global mean pool: segmented (batch sorted), BN4 fused ----------------
__global__ __launch_bounds__(256) void k_pool(const float* __restrict__ y, const float* __restrict__ gam,
                                              const float* __restrict__ bet, const float* __restrict__ s1,
                                              const float* __restrict__ s2, const int* __restrict__ batch,
                                              float* __restrict__ pooled, float* __restrict__ gcnt,
                                              int N, int chunk) {
  __shared__ float aL[DIM], cL[DIM];
  int tid = threadIdx.x;
  if (tid < DIM) {
    float invN = 1.0f / (float)N;
    float m = s1[tid] * invN;
    float var = s2[tid] * invN - m * m;
    float inv = rsqrtf(var + 1e-5f);
    float a = gam[tid] * inv;
    aL[tid] = a;
    cL[tid] = fmaf(-m, a, bet[tid]);
  }
  __syncthreads();
  int wave = tid >> 6, lane = tid & 63;
  int wid = blockIdx.x * 4 + wave;
  int n0 = wid * chunk;
  int n1 = min(N, n0 + chunk);
  if (n0 >= N) return;
  int cur_g = batch[n0];
  float acc = 0.f;
  int cntn = 0;
  for (int n = n0; n < n1; ++n) {
    int gi = batch[n];
    if (gi != cur_g) {
      atomicAdd(&pooled[(size_t)cur_g * DIM + lane], acc);
      if (lane == 0) atomicAdd(&gcnt[cur_g], (float)cntn);
      cur_g = gi; acc = 0.f; cntn = 0;
    }
    acc += fmaf(aL[lane], y[(size_t)n * DIM + lane], cL[lane]);
    ++cntn;
  }
  atomicAdd(&pooled[(size_t)cur_g * DIM + lane], acc);
  if (lane == 0) atomicAdd(&gcnt[cur_g], (float)cntn);
}

// ---------------- head: mean, fc, log_softmax ----------------
__global__ __launch_bounds__(256) void k_head(const float* __restrict__ pooled, const float* __restrict__ gcnt,
                                              const float* __restrict__ fcW, const float* __restrict__ fcb,
                                              float* __restrict__ out, int G, int C) {
  int g = blockIdx.x * 256 + threadIdx.x;
  if (g >= G) return;
  float z[16];
  for (int c = 0; c < C; ++c) z[c] = fcb[c];
  float inv = 1.f / fmaxf(gcnt[g], 1.f);
  for (int f = 0; f < DIM; ++f) {
    float p = pooled[(size_t)g * DIM + f] * inv;
    for (int c = 0; c < C; ++c) z[c] = fmaf(p, fcW[f * C + c], z[c]);
  }
  float m = -1e30f;
  for (int c = 0; c < C; ++c) m = fmaxf(m, z[c]);
  float s = 0.f;
  for (int c = 0; c < C; ++c) s += expf(z[c] - m);
  float ls = logf(s);
  for (int c = 0; c < C; ++c) out[(size_t)g * C + c] = z[c] - m - ls;
}

extern "C" void kernel_launch(void* const* d_in, const int* in_sizes, int n_in,
                              void* d_out, int out_size, void* d_ws, size_t ws_size,
                              hipStream_t stream) {
  const float* x    = (const float*)d_in[0];
  const int*   ei   = (const int*)d_in[1];
  const int*   batch= (const int*)d_in[2];
  const float* W1 = (const float*)d_in[4];
  const float* b1 = (const float*)d_in[5];
  const float* W2 = (const float*)d_in[6];
  const float* b2 = (const float*)d_in[7];
  const float* W3 = (const float*)d_in[8];
  const float* b3 = (const float*)d_in[9];
  const float* W4 = (const float*)d_in[10];
  const float* b4 = (const float*)d_in[11];
  const float* g1 = (const float*)d_in[12];
  const float* be1= (const float*)d_in[13];
  const float* g2 = (const float*)d_in[14];
  const float* be2= (const float*)d_in[15];
  const float* g3 = (const float*)d_in[16];
  const float* be3= (const float*)d_in[17];
  const float* g4 = (const float*)d_in[18];
  const float* be4= (const float*)d_in[19];
  const float* fcW= (const float*)d_in[20];
  const float* fcb= (const float*)d_in[21];
  float* out = (float*)d_out;

  int N   = in_sizes[2];
  int E   = in_sizes[1] / 2;
  int FIN = in_sizes[4] / DIM;
  int C   = in_sizes[21];
  int G   = out_size / C;

  int nbk = (N + 255) >> 8;       // 256-node target buckets

  char* ws = (char*)d_ws;
  size_t off = 0;
  auto alloc = [&](size_t bytes) { size_t o = off; off = (off + bytes + 255) & ~(size_t)255; return o; };
  // zero-init group (must be first / contiguous)
  size_t o_bkc  = alloc((size_t)nbk * 4);
  size_t o_bn   = alloc(4 * 2 * 64 * 4);
  size_t o_pool = alloc((size_t)G * DIM * 4);
  size_t o_gcnt = alloc((size_t)G * 4);
  size_t zero_bytes = off;
  // no-init group
  size_t o_ko   = alloc((size_t)(nbk + 1) * 4);
  size_t o_cur  = alloc((size_t)nbk * 4);
  size_t o_offs = alloc((size_t)N * 4);
  size_t o_cnt  = alloc((size_t)N * 4);
  size_t o_dis  = alloc((size_t)N * 4);
  size_t o_recs = alloc((size_t)E * 4);
  size_t o_csr  = alloc((size_t)E * 4);
  size_t o_xl   = alloc((size_t)N * DIM * 2);   // fp16
  size_t o_y    = alloc((size_t)N * DIM * 4);
  (void)ws_size;

  int*    bkcnt  = (int*)(ws + o_bkc);
  float*  bn     = (float*)(ws + o_bn);
  float*  pooled = (float*)(ws + o_pool);
  float*  gcnt   = (float*)(ws + o_gcnt);
  int*    keyoffs= (int*)(ws + o_ko);
  int*    bcur   = (int*)(ws + o_cur);
  int*    offs   = (int*)(ws + o_offs);
  int*    cnt    = (int*)(ws + o_cnt);
  float*  dis    = (float*)(ws + o_dis);
  uint32* recs   = (uint32*)(ws + o_recs);
  int*    csrs   = (int*)(ws + o_csr);
  f16*    xl     = (f16*)(ws + o_xl);
  float*  y      = (float*)(ws + o_y);

  hipMemsetAsync(d_ws, 0, zero_bytes, stream);

  const int* row  = ei;
  const int* colp = ei + E;
  int pblk = (E + PCHUNK - 1) / PCHUNK;

  k_hist<<<pblk, 256, 0, stream>>>(colp, bkcnt, E, nbk);
  k_scank<<<1, 256, 0, stream>>>(bkcnt, keyoffs, bcur, nbk);
  k_part<<<pblk, 256, 0, stream>>>(row, colp, bcur, recs, E, nbk);
  k_sort2<<<nbk, 256, 0, stream>>>(recs, keyoffs, csrs, offs, cnt, dis, N);

  // Layer 1
  k_gemm_in<<<1024, 256, 0, stream>>>(x, W1, dis, xl, N, FIN);
  k_agg<<<2048, 256, 0, stream>>>(xl, offs, cnt, csrs, dis, b1, y, bn + 0, bn + 64, N);
  // Layer 2 (applies BN1 on the fly)
  k_gemm_bn<<<2048, 256, 0, stream>>>(y, W2, g1, be1, bn + 0, bn + 64, dis, xl, N);
  k_agg<<<2048, 256, 0, stream>>>(xl, offs, cnt, csrs, dis, b2, y, bn + 128, bn + 192, N);
  // Layer 3
  k_gemm_bn<<<2048, 256, 0, stream>>>(y, W3, g2, be2, bn + 128, bn + 192, dis, xl, N);
  k_agg<<<2048, 256, 0, stream>>>(xl, offs, cnt, csrs, dis, b3, y, bn + 256, bn + 320, N);
  // Layer 4
  k_gemm_bn<<<2048, 256, 0, stream>>>(y, W4, g3, be3, bn + 256, bn + 320, dis, xl, N);
  k_agg<<<2048, 256, 0, stream>>>(xl, offs, cnt, csrs, dis, b4, y, bn + 384, bn + 448, N);
  // Pool (applies BN4) + head
  int nwaves = 2048;
  int chunk = (N + nwaves - 1) / nwaves;
  k_pool<<<nwaves / 4, 256, 0, stream>>>(y, g4, be4, bn + 384, bn + 448, batch, pooled, gcnt, N, chunk);
  k_head<<<(G + 255) / 256, 256, 0, stream>>>(pooled, gcnt, fcW, fcb, out, G, C);
}